// Round 10
// baseline (352.494 us; speedup 1.0000x reference)
//
#include <hip/hip_runtime.h>
#include <hip/hip_bf16.h>

typedef unsigned short u16;
typedef unsigned int u32;
typedef float f32x4 __attribute__((ext_vector_type(4)));
typedef short bf16x8 __attribute__((ext_vector_type(8)));

// ---- constants (B=2, S=2048, E=1024, H=16, D=64) ----
#define BB 2
#define SS 2048
#define EE 1024
#define HH 16
#define DD 64
// q pre-scale: 1/sqrt(D) * log2(e) — scores land directly in exp2 domain.
#define QSCALE 0.18033688011f

__device__ __forceinline__ u16 f2bf(float f) {
    union { u32 i; float f; } x; x.f = f;
    return (u16)((x.i + 0x7FFFu + ((x.i >> 16) & 1u)) >> 16);
}
__device__ __forceinline__ u32 pkbf(float a, float b) {
    __hip_bfloat162 h = __float22bfloat162_rn(make_float2(a, b));
    union { __hip_bfloat162 h; u32 u; } c; c.h = h; return c.u;
}

#define MFMA16(a, b, c) __builtin_amdgcn_mfma_f32_16x16x32_bf16((a), (b), (c), 0, 0, 0)

// async global->LDS DMA, 16B per lane; LDS dest = wave-uniform base + lane*16
__device__ __forceinline__ void gld16(const u16* g, u16* l) {
    __builtin_amdgcn_global_load_lds(
        (const __attribute__((address_space(1))) void*)g,
        (__attribute__((address_space(3))) void*)l,
        16, 0, 0);
}

// ============================================================
// fused fp32 -> bf16 convert of x | W_attn | W_proj into contiguous ws
// ============================================================
__global__ __launch_bounds__(256) void convert_all(
    const float* __restrict__ x, const float* __restrict__ wa,
    const float* __restrict__ wp, u16* __restrict__ dst)
{
    const size_t n0 = (size_t)4096 * 1024;
    const size_t n1 = n0 + (size_t)3072 * 1024;
    size_t i = ((size_t)blockIdx.x * 256 + threadIdx.x) * 4;
    const float* s;
    size_t off;
    if (i < n0)      { s = x;  off = 0;  }
    else if (i < n1) { s = wa; off = n0; }
    else             { s = wp; off = n1; }
    float4 v = *(const float4*)(s + (i - off));
    uint2 o;
    o.x = pkbf(v.x, v.y);
    o.y = pkbf(v.z, v.w);
    *(uint2*)(dst + i) = o;
}

// ============================================================
// MFMA GEMM core v2 (NT, bf16): C[m][n] = sum_k A[m][k]*B[n][k]
// BM=BN=128, BK=64, 4 waves (2x2), 4x4 frags/wave, 32 MFMA/k-iter/wave.
// Staging: global_load_lds 16B, XOR-swizzled unpadded [128][64] LDS.
// ============================================================
#define GEMM_CORE(Aptr, Bptr, m0, n0)                                          \
    __shared__ __align__(16) u16 As[128 * 64];                                 \
    __shared__ __align__(16) u16 Bs[128 * 64];                                 \
    const int tid = threadIdx.x;                                               \
    const int wave = tid >> 6, lane = tid & 63;                                \
    const int l16 = lane & 15, quad = lane >> 4;                               \
    const int wm = wave >> 1, wn = wave & 1;                                   \
    const int ldr = lane >> 3;                                                 \
    const int csw = ((lane & 7) ^ ldr) * 8;  /* swizzled k-chunk (elems) */    \
    f32x4 acc[4][4];                                                           \
    _Pragma("unroll") for (int i = 0; i < 4; ++i)                              \
        _Pragma("unroll") for (int j = 0; j < 4; ++j)                          \
            acc[i][j] = f32x4{0.f, 0.f, 0.f, 0.f};                             \
    for (int k0 = 0; k0 < 1024; k0 += 64) {                                    \
        __syncthreads();                                                       \
        _Pragma("unroll") for (int t = 0; t < 4; ++t) {                        \
            const int a0 = wave * 4 + t;                                       \
            const int row = a0 * 8 + ldr;                                      \
            gld16(Aptr + (size_t)(m0 + row) * 1024 + k0 + csw,                 \
                  &As[a0 * 512 + lane * 8]);                                   \
            gld16(Bptr + (size_t)(n0 + row) * 1024 + k0 + csw,                 \
                  &Bs[a0 * 512 + lane * 8]);                                   \
        }                                                                      \
        __syncthreads();                                                       \
        _Pragma("unroll") for (int ks = 0; ks < 2; ++ks) {                     \
            bf16x8 af[4], bf[4];                                               \
            _Pragma("unroll") for (int i = 0; i < 4; ++i)                      \
                af[i] = *(const bf16x8*)&As[(wm * 64 + i * 16 + l16) * 64 +    \
                                            ((ks * 4 + quad) ^ (l16 & 7)) * 8]; \
            _Pragma("unroll") for (int j = 0; j < 4; ++j)                      \
                bf[j] = *(const bf16x8*)&Bs[(wn * 64 + j * 16 + l16) * 64 +    \
                                            ((ks * 4 + quad) ^ (l16 & 7)) * 8]; \
            _Pragma("unroll") for (int i = 0; i < 4; ++i)                      \
                _Pragma("unroll") for (int j = 0; j < 4; ++j)                  \
                    acc[i][j] = MFMA16(af[i], bf[j], acc[i][j]);               \
        }                                                                      \
    }

// ============================================================
// GEMM1: qkv = x*W_attn^T + b_attn. q (pre-scaled QSCALE) / k -> [B,H,S,D];
// v -> V^T [B,H,D,S] via LDS transpose (coalesced 8B stores). grid (24, 32)
// ============================================================
__global__ __launch_bounds__(256) void gemm_qkv(
    const u16* __restrict__ A, const u16* __restrict__ B, const float* __restrict__ bias,
    u16* __restrict__ Qo, u16* __restrict__ Ko, u16* __restrict__ Vto)
{
    __shared__ __align__(16) u16 T[128 * 76];         // v-transpose buffer
    const int n0 = blockIdx.x * 128, m0 = blockIdx.y * 128;
    GEMM_CORE(A, B, m0, n0)
    const int part = blockIdx.x >> 3;                 // 0=q,1=k,2=v
    if (part != 2) {
        const int h = ((blockIdx.x & 7) << 1) | wn;   // head (uniform per wave)
#pragma unroll
        for (int j = 0; j < 4; ++j) {
            const int f = n0 + wn * 64 + j * 16 + l16;
            const int d = j * 16 + l16;
            const float bj = bias[f];
#pragma unroll
            for (int i = 0; i < 4; ++i) {
#pragma unroll
                for (int r = 0; r < 4; ++r) {
                    const int m = m0 + wm * 64 + i * 16 + quad * 4 + r;
                    const int b = m >> 11, s = m & 2047;
                    const float val = acc[i][j][r] + bj;
                    if (part == 0)
                        Qo[(((size_t)(b * HH + h)) * SS + s) * DD + d] = f2bf(val * QSCALE);
                    else
                        Ko[(((size_t)(b * HH + h)) * SS + s) * DD + d] = f2bf(val);
                }
            }
        }
    } else {
        // V: transpose C-tile (128 m x 128 f) through LDS, store [B,H,D,S]
        const int hbase = (blockIdx.x & 7) << 1;
#pragma unroll
        for (int wmr = 0; wmr < 2; ++wmr) {
            __syncthreads();
            if (wm == wmr) {
#pragma unroll
                for (int j = 0; j < 4; ++j) {
                    const float bj = bias[n0 + wn * 64 + j * 16 + l16];
#pragma unroll
                    for (int i = 0; i < 4; ++i) {
                        uint2 pw;
                        pw.x = pkbf(acc[i][j][0] + bj, acc[i][j][1] + bj);
                        pw.y = pkbf(acc[i][j][2] + bj, acc[i][j][3] + bj);
                        *(uint2*)&T[(wn * 64 + j * 16 + l16) * 76 + i * 16 + quad * 4] = pw;
                    }
                }
            }
            __syncthreads();
            const int frow = tid >> 1;                // 0..127 (f_local)
            const int h = hbase + (frow >> 6);
            const int d = frow & 63;
            const int mg = m0 + wmr * 64;
            const int b = mg >> 11, sbase = mg & 2047;
            u16* dstrow = Vto + (((size_t)(b * HH + h)) * DD + d) * SS + sbase;
#pragma unroll
            for (int l = 0; l < 8; ++l) {
                const int mo = (tid & 1) * 32 + l * 4;
                *(uint2*)(dstrow + mo) = *(const uint2*)&T[frow * 76 + mo];
            }
        }
    }
}

// ============================================================
// GEMM2: out = o*W_proj^T + b_proj (fp32 out). grid (8, 32)
// ============================================================
__global__ __launch_bounds__(256) void gemm_proj(
    const u16* __restrict__ A, const u16* __restrict__ B, const float* __restrict__ bias,
    float* __restrict__ out)
{
    const int n0 = blockIdx.x * 128, m0 = blockIdx.y * 128;
    GEMM_CORE(A, B, m0, n0)
#pragma unroll
    for (int j = 0; j < 4; ++j) {
        const int f = n0 + wn * 64 + j * 16 + l16;
        const float bj = bias[f];
#pragma unroll
        for (int i = 0; i < 4; ++i) {
#pragma unroll
            for (int r = 0; r < 4; ++r) {
                const int m = m0 + wm * 64 + i * 16 + quad * 4 + r;
                out[(size_t)m * EE + f] = acc[i][j][r] + bj;
            }
        }
    }
}

// ============================================================
// MFMA flash attention v4, causal — r8 structure + in-block split-K.
// 512 threads = 8 waves: waves 0-3 process EVEN kb tiles, waves 4-7 ODD.
// No-max softmax makes partials additive: O = (O_e + O_o) / (l_e + l_o),
// combined once at the end through LDS. Iterations halve (33 -> ~17),
// waves/CU double (8 -> 16) -> latency hiding doubles.
// Paired q-tiles (qbA=bx, qbB=31-bx) share staged K/V; per-lane softmax
// state; Ps wave-private (lgkm ordering only).
// grid (16,32) = 512 blocks x 8 waves; LDS 68 KB -> 2 blocks/CU.
// ============================================================
__global__ __launch_bounds__(512, 4) void attn(
    const u16* __restrict__ Q, const u16* __restrict__ K, const u16* __restrict__ VT,
    u16* __restrict__ O)
{
    const int qbA = blockIdx.x;            // 0..15 (short tile)
    const int qbB = 31 - qbA;              // 16..31 (long tile)
    const int bh = blockIdx.y;
    const int tid = threadIdx.x;
    const int wave = tid >> 6, lane = tid & 63;
    const int w4 = wave & 3, half = wave >> 2;   // half 0: even kb, 1: odd kb
    const int l16 = lane & 15, quad = lane >> 4;
    const int ldr = lane >> 3;
    const int csw = ((lane & 7) ^ ldr) * 8;

    // LDS carve: 4 K/V tiles (even/odd) + 4 Ps buffers = 69632 B.
    // Epilogue partial-exchange buffer (34816 B) aliases the front.
    __shared__ __align__(16) u16 SMEM[34816];
    u16* Kse  = SMEM;                 // 64*64
    u16* Vtse = SMEM + 4096;
    u16* Kso  = SMEM + 8192;
    u16* Vtso = SMEM + 12288;
    u16* PsAe = SMEM + 16384;         // 64*72
    u16* PsBe = SMEM + 20992;
    u16* PsAo = SMEM + 25600;
    u16* PsBo = SMEM + 30208;
    u16* Ks  = half ? Kso  : Kse;
    u16* Vts = half ? Vtso : Vtse;
    u16* PsA = half ? PsAo : PsAe;
    u16* PsB = half ? PsBo : PsBe;

    const u16* qptr = Q + (size_t)bh * SS * DD;
    const u16* kptr = K + (size_t)bh * SS * DD;
    const u16* vtptr = VT + (size_t)bh * DD * SS;

    const int qrowA = qbA * 64 + w4 * 16 + l16;
    const int qrowB = qbB * 64 + w4 * 16 + l16;
    bf16x8 bqA[2], bqB[2];
#pragma unroll
    for (int ks = 0; ks < 2; ++ks) {
        bqA[ks] = *(const bf16x8*)(qptr + (size_t)qrowA * DD + ks * 32 + quad * 8);
        bqB[ks] = *(const bf16x8*)(qptr + (size_t)qrowB * DD + ks * 32 + quad * 8);
    }

    float lAp = 0.f, lBp = 0.f;            // per-lane partial l (this half)
    f32x4 oA[4], oB[4];
#pragma unroll
    for (int j = 0; j < 4; ++j) { oA[j] = f32x4{0.f, 0.f, 0.f, 0.f}; oB[j] = f32x4{0.f, 0.f, 0.f, 0.f}; }

    const int nI = (qbB >> 1) + 1;         // even-kb count; odd count <= nI
    for (int i = 0; i < nI; ++i) {
        const int kbe = 2 * i, kbo = 2 * i + 1;
        __syncthreads();
        {   // stage 4 tiles across 8 waves (tile = wave>>1)
            const int tilesel = wave >> 1, sub = wave & 1;
#pragma unroll
            for (int t = 0; t < 4; ++t) {
                const int a0 = sub * 4 + t;
                const int row = a0 * 8 + ldr;
                if (tilesel == 0)
                    gld16(kptr + (size_t)(kbe * 64 + row) * DD + csw, &Kse[a0 * 512 + lane * 8]);
                else if (tilesel == 1)
                    gld16(vtptr + (size_t)row * SS + kbe * 64 + csw, &Vtse[a0 * 512 + lane * 8]);
                else if (tilesel == 2) {
                    if (kbo <= qbB)
                        gld16(kptr + (size_t)(kbo * 64 + row) * DD + csw, &Kso[a0 * 512 + lane * 8]);
                } else {
                    if (kbo <= qbB)
                        gld16(vtptr + (size_t)row * SS + kbo * 64 + csw, &Vtso[a0 * 512 + lane * 8]);
                }
            }
        }
        __syncthreads();

        const int kb = 2 * i + half;       // this half's tile
        if (kb <= qbB) {
            const int k0 = kb * 64;
            const bool doA = (kb <= qbA);

            // S^T = K·Q^T for both q-tiles (K-frags shared)
            f32x4 sA[4], sB[4];
#pragma unroll
            for (int j = 0; j < 4; ++j) { sA[j] = f32x4{0.f, 0.f, 0.f, 0.f}; sB[j] = f32x4{0.f, 0.f, 0.f, 0.f}; }
#pragma unroll
            for (int ks = 0; ks < 2; ++ks) {
#pragma unroll
                for (int j = 0; j < 4; ++j) {
                    bf16x8 ak = *(const bf16x8*)&Ks[(j * 16 + l16) * 64 +
                                                    ((ks * 4 + quad) ^ (l16 & 7)) * 8];
                    sB[j] = MFMA16(ak, bqB[ks], sB[j]);
                    if (doA) sA[j] = MFMA16(ak, bqA[ks], sA[j]);
                }
            }

            // ---- no-max softmax B ----
            {
                if (kb == qbB) {
#pragma unroll
                    for (int j = 0; j < 4; ++j)
#pragma unroll
                        for (int r = 0; r < 4; ++r) {
                            const int key = k0 + j * 16 + quad * 4 + r;
                            if (key > qrowB) sB[j][r] = -INFINITY;   // exp2 -> 0
                        }
                }
#pragma unroll
                for (int j = 0; j < 4; ++j) {
                    const float p0 = __builtin_amdgcn_exp2f(sB[j][0]);
                    const float p1 = __builtin_amdgcn_exp2f(sB[j][1]);
                    const float p2 = __builtin_amdgcn_exp2f(sB[j][2]);
                    const float p3 = __builtin_amdgcn_exp2f(sB[j][3]);
                    lBp += (p0 + p1) + (p2 + p3);
                    uint2 pw; pw.x = pkbf(p0, p1); pw.y = pkbf(p2, p3);
                    *(uint2*)&PsB[(w4 * 16 + l16) * 72 + j * 16 + quad * 4] = pw;
                }
            }
            // ---- no-max softmax A ----
            if (doA) {
                if (kb == qbA) {
#pragma unroll
                    for (int j = 0; j < 4; ++j)
#pragma unroll
                        for (int r = 0; r < 4; ++r) {
                            const int key = k0 + j * 16 + quad * 4 + r;
                            if (key > qrowA) sA[j][r] = -INFINITY;
                        }
                }
#pragma unroll
                for (int j = 0; j < 4; ++j) {
                    const float p0 = __builtin_amdgcn_exp2f(sA[j][0]);
                    const float p1 = __builtin_amdgcn_exp2f(sA[j][1]);
                    const float p2 = __builtin_amdgcn_exp2f(sA[j][2]);
                    const float p3 = __builtin_amdgcn_exp2f(sA[j][3]);
                    lAp += (p0 + p1) + (p2 + p3);
                    uint2 pw; pw.x = pkbf(p0, p1); pw.y = pkbf(p2, p3);
                    *(uint2*)&PsA[(w4 * 16 + l16) * 72 + j * 16 + quad * 4] = pw;
                }
            }

            // O^T += V^T·P^T (Ps wave-private: lgkm ordering suffices)
#pragma unroll
            for (int ks = 0; ks < 2; ++ks) {
                bf16x8 bpB = *(const bf16x8*)&PsB[(w4 * 16 + l16) * 72 + ks * 32 + quad * 8];
                bf16x8 bpA;
                if (doA) bpA = *(const bf16x8*)&PsA[(w4 * 16 + l16) * 72 + ks * 32 + quad * 8];
#pragma unroll
                for (int j = 0; j < 4; ++j) {
                    bf16x8 av = *(const bf16x8*)&Vts[(j * 16 + l16) * 64 +
                                                     ((ks * 4 + quad) ^ (l16 & 7)) * 8];
                    oB[j] = MFMA16(av, bpB, oB[j]);
                    if (doA) oA[j] = MFMA16(av, bpA, oA[j]);
                }
            }
        }
    }

    // ---- combine halves through LDS (additive: no-max softmax) ----
    __syncthreads();
    float* FP = (float*)SMEM;              // 256 slots * 34 floats = 34816 B
    const int slot = (w4 * 64 + lane) * 34;
    if (half == 1) {
#pragma unroll
        for (int j = 0; j < 4; ++j)
#pragma unroll
            for (int r = 0; r < 4; ++r) {
                FP[slot + j * 4 + r] = oA[j][r];
                FP[slot + 16 + j * 4 + r] = oB[j][r];
            }
        FP[slot + 32] = lAp;
        FP[slot + 33] = lBp;
    }
    __syncthreads();
    if (half == 0) {
#pragma unroll
        for (int j = 0; j < 4; ++j)
#pragma unroll
            for (int r = 0; r < 4; ++r) {
                oA[j][r] += FP[slot + j * 4 + r];
                oB[j][r] += FP[slot + 16 + j * 4 + r];
            }
        lAp += FP[slot + 32];
        lBp += FP[slot + 33];

        const int b = bh >> 4, h = bh & 15;
        {
            float l = lBp;
            l += __shfl_xor(l, 16);
            l += __shfl_xor(l, 32);
            const float inv = 1.0f / l;
#pragma unroll
            for (int j = 0; j < 4; ++j) {
                uint2 o4;
                o4.x = pkbf(oB[j][0] * inv, oB[j][1] * inv);
                o4.y = pkbf(oB[j][2] * inv, oB[j][3] * inv);
                *(uint2*)&O[((size_t)(b * SS + qrowB)) * EE + h * DD + j * 16 + quad * 4] = o4;
            }
        }
        {
            float l = lAp;
            l += __shfl_xor(l, 16);
            l += __shfl_xor(l, 32);
            const float inv = 1.0f / l;
#pragma unroll
            for (int j = 0; j < 4; ++j) {
                uint2 o4;
                o4.x = pkbf(oA[j][0] * inv, oA[j][1] * inv);
                o4.y = pkbf(oA[j][2] * inv, oA[j][3] * inv);
                *(uint2*)&O[((size_t)(b * SS + qrowA)) * EE + h * DD + j * 16 + quad * 4] = o4;
            }
        }
    }
}

extern "C" void kernel_launch(void* const* d_in, const int* in_sizes, int n_in,
                              void* d_out, int out_size, void* d_ws, size_t ws_size,
                              hipStream_t stream) {
    const float* x      = (const float*)d_in[0];  // [B,S,E] fp32
    const float* W_attn = (const float*)d_in[1];  // [3E,E] fp32
    const float* b_attn = (const float*)d_in[2];  // [3E] fp32
    const float* W_proj = (const float*)d_in[3];  // [E,E] fp32
    const float* b_proj = (const float*)d_in[4];  // [E] fp32
    float* out = (float*)d_out;                   // fp32 [B,S,E]

    // ws layout (u16 elems): xb 4.19M | wab 3.15M | wpb 1.05M | q 4.19M | k 4.19M | vt 4.19M
    u16* xb  = (u16*)d_ws;
    u16* wab = xb + (size_t)4096 * 1024;
    u16* wpb = wab + (size_t)3072 * 1024;
    u16* qw  = wpb + (size_t)1024 * 1024;
    u16* kw  = qw + (size_t)BB * HH * SS * DD;
    u16* vtw = kw + (size_t)BB * HH * SS * DD;
    u16* ow  = xb;                                 // xb dead after gemm_qkv

    convert_all<<<8192, 256, 0, stream>>>(x, W_attn, W_proj, xb);
    gemm_qkv<<<dim3(24, 32), 256, 0, stream>>>(xb, wab, b_attn, qw, kw, vtw);
    attn<<<dim3(16, 32), 512, 0, stream>>>(qw, kw, vtw, ow);
    gemm_proj<<<dim3(8, 32), 256, 0, stream>>>(ow, wpb, b_proj, out);
}

// Round 11
// 213.781 us; speedup vs baseline: 1.6489x; 1.6489x over previous
//
#include <hip/hip_runtime.h>
#include <hip/hip_bf16.h>

typedef unsigned short u16;
typedef unsigned int u32;
typedef float f32x4 __attribute__((ext_vector_type(4)));
typedef short bf16x8 __attribute__((ext_vector_type(8)));

// ---- constants (B=2, S=2048, E=1024, H=16, D=64) ----
#define BB 2
#define SS 2048
#define EE 1024
#define HH 16
#define DD 64
// q pre-scale: 1/sqrt(D) * log2(e) — scores land directly in exp2 domain.
#define QSCALE 0.18033688011f

__device__ __forceinline__ u16 f2bf(float f) {
    union { u32 i; float f; } x; x.f = f;
    return (u16)((x.i + 0x7FFFu + ((x.i >> 16) & 1u)) >> 16);
}
__device__ __forceinline__ u32 pkbf(float a, float b) {
    __hip_bfloat162 h = __float22bfloat162_rn(make_float2(a, b));
    union { __hip_bfloat162 h; u32 u; } c; c.h = h; return c.u;
}

#define MFMA16(a, b, c) __builtin_amdgcn_mfma_f32_16x16x32_bf16((a), (b), (c), 0, 0, 0)

// async global->LDS DMA, 16B per lane; LDS dest = wave-uniform base + lane*16
__device__ __forceinline__ void gld16(const u16* g, u16* l) {
    __builtin_amdgcn_global_load_lds(
        (const __attribute__((address_space(1))) void*)g,
        (__attribute__((address_space(3))) void*)l,
        16, 0, 0);
}

// ============================================================
// fused fp32 -> bf16 convert of x | W_attn | W_proj into contiguous ws
// ============================================================
__global__ __launch_bounds__(256) void convert_all(
    const float* __restrict__ x, const float* __restrict__ wa,
    const float* __restrict__ wp, u16* __restrict__ dst)
{
    const size_t n0 = (size_t)4096 * 1024;
    const size_t n1 = n0 + (size_t)3072 * 1024;
    size_t i = ((size_t)blockIdx.x * 256 + threadIdx.x) * 4;
    const float* s;
    size_t off;
    if (i < n0)      { s = x;  off = 0;  }
    else if (i < n1) { s = wa; off = n0; }
    else             { s = wp; off = n1; }
    float4 v = *(const float4*)(s + (i - off));
    uint2 o;
    o.x = pkbf(v.x, v.y);
    o.y = pkbf(v.z, v.w);
    *(uint2*)(dst + i) = o;
}

// ============================================================
// MFMA GEMM core v2 (NT, bf16): C[m][n] = sum_k A[m][k]*B[n][k]
// BM=BN=128, BK=64, 4 waves (2x2), 4x4 frags/wave, 32 MFMA/k-iter/wave.
// Staging: global_load_lds 16B, XOR-swizzled unpadded [128][64] LDS.
// ============================================================
#define GEMM_CORE(Aptr, Bptr, m0, n0)                                          \
    __shared__ __align__(16) u16 As[128 * 64];                                 \
    __shared__ __align__(16) u16 Bs[128 * 64];                                 \
    const int tid = threadIdx.x;                                               \
    const int wave = tid >> 6, lane = tid & 63;                                \
    const int l16 = lane & 15, quad = lane >> 4;                               \
    const int wm = wave >> 1, wn = wave & 1;                                   \
    const int ldr = lane >> 3;                                                 \
    const int csw = ((lane & 7) ^ ldr) * 8;  /* swizzled k-chunk (elems) */    \
    f32x4 acc[4][4];                                                           \
    _Pragma("unroll") for (int i = 0; i < 4; ++i)                              \
        _Pragma("unroll") for (int j = 0; j < 4; ++j)                          \
            acc[i][j] = f32x4{0.f, 0.f, 0.f, 0.f};                             \
    for (int k0 = 0; k0 < 1024; k0 += 64) {                                    \
        __syncthreads();                                                       \
        _Pragma("unroll") for (int t = 0; t < 4; ++t) {                        \
            const int a0 = wave * 4 + t;                                       \
            const int row = a0 * 8 + ldr;                                      \
            gld16(Aptr + (size_t)(m0 + row) * 1024 + k0 + csw,                 \
                  &As[a0 * 512 + lane * 8]);                                   \
            gld16(Bptr + (size_t)(n0 + row) * 1024 + k0 + csw,                 \
                  &Bs[a0 * 512 + lane * 8]);                                   \
        }                                                                      \
        __syncthreads();                                                       \
        _Pragma("unroll") for (int ks = 0; ks < 2; ++ks) {                     \
            bf16x8 af[4], bf[4];                                               \
            _Pragma("unroll") for (int i = 0; i < 4; ++i)                      \
                af[i] = *(const bf16x8*)&As[(wm * 64 + i * 16 + l16) * 64 +    \
                                            ((ks * 4 + quad) ^ (l16 & 7)) * 8]; \
            _Pragma("unroll") for (int j = 0; j < 4; ++j)                      \
                bf[j] = *(const bf16x8*)&Bs[(wn * 64 + j * 16 + l16) * 64 +    \
                                            ((ks * 4 + quad) ^ (l16 & 7)) * 8]; \
            _Pragma("unroll") for (int i = 0; i < 4; ++i)                      \
                _Pragma("unroll") for (int j = 0; j < 4; ++j)                  \
                    acc[i][j] = MFMA16(af[i], bf[j], acc[i][j]);               \
        }                                                                      \
    }

// ============================================================
// GEMM1: qkv = x*W_attn^T + b_attn. q (pre-scaled QSCALE) / k -> [B,H,S,D];
// v -> V^T [B,H,D,S] via LDS transpose (coalesced 8B stores). grid (24, 32)
// ============================================================
__global__ __launch_bounds__(256) void gemm_qkv(
    const u16* __restrict__ A, const u16* __restrict__ B, const float* __restrict__ bias,
    u16* __restrict__ Qo, u16* __restrict__ Ko, u16* __restrict__ Vto)
{
    __shared__ __align__(16) u16 T[128 * 76];         // v-transpose buffer
    const int n0 = blockIdx.x * 128, m0 = blockIdx.y * 128;
    GEMM_CORE(A, B, m0, n0)
    const int part = blockIdx.x >> 3;                 // 0=q,1=k,2=v
    if (part != 2) {
        const int h = ((blockIdx.x & 7) << 1) | wn;   // head (uniform per wave)
#pragma unroll
        for (int j = 0; j < 4; ++j) {
            const int f = n0 + wn * 64 + j * 16 + l16;
            const int d = j * 16 + l16;
            const float bj = bias[f];
#pragma unroll
            for (int i = 0; i < 4; ++i) {
#pragma unroll
                for (int r = 0; r < 4; ++r) {
                    const int m = m0 + wm * 64 + i * 16 + quad * 4 + r;
                    const int b = m >> 11, s = m & 2047;
                    const float val = acc[i][j][r] + bj;
                    if (part == 0)
                        Qo[(((size_t)(b * HH + h)) * SS + s) * DD + d] = f2bf(val * QSCALE);
                    else
                        Ko[(((size_t)(b * HH + h)) * SS + s) * DD + d] = f2bf(val);
                }
            }
        }
    } else {
        // V: transpose C-tile (128 m x 128 f) through LDS, store [B,H,D,S]
        const int hbase = (blockIdx.x & 7) << 1;
#pragma unroll
        for (int wmr = 0; wmr < 2; ++wmr) {
            __syncthreads();
            if (wm == wmr) {
#pragma unroll
                for (int j = 0; j < 4; ++j) {
                    const float bj = bias[n0 + wn * 64 + j * 16 + l16];
#pragma unroll
                    for (int i = 0; i < 4; ++i) {
                        uint2 pw;
                        pw.x = pkbf(acc[i][j][0] + bj, acc[i][j][1] + bj);
                        pw.y = pkbf(acc[i][j][2] + bj, acc[i][j][3] + bj);
                        *(uint2*)&T[(wn * 64 + j * 16 + l16) * 76 + i * 16 + quad * 4] = pw;
                    }
                }
            }
            __syncthreads();
            const int frow = tid >> 1;                // 0..127 (f_local)
            const int h = hbase + (frow >> 6);
            const int d = frow & 63;
            const int mg = m0 + wmr * 64;
            const int b = mg >> 11, sbase = mg & 2047;
            u16* dstrow = Vto + (((size_t)(b * HH + h)) * DD + d) * SS + sbase;
#pragma unroll
            for (int l = 0; l < 8; ++l) {
                const int mo = (tid & 1) * 32 + l * 4;
                *(uint2*)(dstrow + mo) = *(const uint2*)&T[frow * 76 + mo];
            }
        }
    }
}

// ============================================================
// GEMM2: out = o*W_proj^T + b_proj (fp32 out). grid (8, 32)
// ============================================================
__global__ __launch_bounds__(256) void gemm_proj(
    const u16* __restrict__ A, const u16* __restrict__ B, const float* __restrict__ bias,
    float* __restrict__ out)
{
    const int n0 = blockIdx.x * 128, m0 = blockIdx.y * 128;
    GEMM_CORE(A, B, m0, n0)
#pragma unroll
    for (int j = 0; j < 4; ++j) {
        const int f = n0 + wn * 64 + j * 16 + l16;
        const float bj = bias[f];
#pragma unroll
        for (int i = 0; i < 4; ++i) {
#pragma unroll
            for (int r = 0; r < 4; ++r) {
                const int m = m0 + wm * 64 + i * 16 + quad * 4 + r;
                out[(size_t)m * EE + f] = acc[i][j][r] + bj;
            }
        }
    }
}

// ============================================================
// MFMA flash attention v5, causal — r8 loop body, ONE q-tile per block.
// Un-pairing halves per-wave state (VGPR ~100 -> ~65, no spill) and
// doubles block count: grid (32,32) = 1024 blocks, 17.4 KB LDS ->
// 4 blocks/CU resident (16 waves/CU, 2x r8). qb = 31-bx launches the
// longest blocks first; 4-deep backfill absorbs causal imbalance.
// Staged K/V volume identical to r8 (pairing never saved traffic).
// No-max softmax (bounded scores), per-lane l, quad-reduced once at end.
// ============================================================
__global__ __launch_bounds__(256, 4) void attn(
    const u16* __restrict__ Q, const u16* __restrict__ K, const u16* __restrict__ VT,
    u16* __restrict__ O)
{
    const int qb = 31 - (int)blockIdx.x;   // longest first
    const int bh = blockIdx.y;
    const int tid = threadIdx.x;
    const int wave = tid >> 6, lane = tid & 63;
    const int l16 = lane & 15, quad = lane >> 4;
    const int ldr = lane >> 3;
    const int csw = ((lane & 7) ^ ldr) * 8;
    __shared__ __align__(16) u16 Ks[64 * 64];
    __shared__ __align__(16) u16 Vts[64 * 64];
    __shared__ __align__(16) u16 Ps[64 * 72];

    const u16* qptr = Q + (size_t)bh * SS * DD;
    const u16* kptr = K + (size_t)bh * SS * DD;
    const u16* vtptr = VT + (size_t)bh * DD * SS;

    const int qrow = qb * 64 + wave * 16 + l16;   // this lane's query
    bf16x8 bq[2];
#pragma unroll
    for (int ks = 0; ks < 2; ++ks)
        bq[ks] = *(const bf16x8*)(qptr + (size_t)qrow * DD + ks * 32 + quad * 8);

    float lp = 0.f;                        // per-lane partial l
    f32x4 o_acc[4];
#pragma unroll
    for (int j = 0; j < 4; ++j) o_acc[j] = f32x4{0.f, 0.f, 0.f, 0.f};

    for (int kb = 0; kb <= qb; ++kb) {
        const int k0 = kb * 64;
        __syncthreads();
#pragma unroll
        for (int t = 0; t < 2; ++t) {
            const int a0 = wave * 2 + t;
            const int row = a0 * 8 + ldr;
            gld16(kptr + (size_t)(k0 + row) * DD + csw, &Ks[a0 * 512 + lane * 8]);
            gld16(vtptr + (size_t)row * SS + k0 + csw, &Vts[a0 * 512 + lane * 8]);
        }
        __syncthreads();

        // S^T = K·Q^T
        f32x4 s[4];
#pragma unroll
        for (int j = 0; j < 4; ++j) s[j] = f32x4{0.f, 0.f, 0.f, 0.f};
#pragma unroll
        for (int ks = 0; ks < 2; ++ks) {
#pragma unroll
            for (int j = 0; j < 4; ++j) {
                bf16x8 ak = *(const bf16x8*)&Ks[(j * 16 + l16) * 64 +
                                                ((ks * 4 + quad) ^ (l16 & 7)) * 8];
                s[j] = MFMA16(ak, bq[ks], s[j]);
            }
        }

        // ---- no-max softmax: p = exp2(s'), mask only on the diagonal tile ----
        if (kb == qb) {
#pragma unroll
            for (int j = 0; j < 4; ++j)
#pragma unroll
                for (int r = 0; r < 4; ++r) {
                    const int key = k0 + j * 16 + quad * 4 + r;
                    if (key > qrow) s[j][r] = -INFINITY;   // exp2 -> 0
                }
        }
#pragma unroll
        for (int j = 0; j < 4; ++j) {
            const float p0 = __builtin_amdgcn_exp2f(s[j][0]);
            const float p1 = __builtin_amdgcn_exp2f(s[j][1]);
            const float p2 = __builtin_amdgcn_exp2f(s[j][2]);
            const float p3 = __builtin_amdgcn_exp2f(s[j][3]);
            lp += (p0 + p1) + (p2 + p3);
            uint2 pw; pw.x = pkbf(p0, p1); pw.y = pkbf(p2, p3);
            *(uint2*)&Ps[(wave * 16 + l16) * 72 + j * 16 + quad * 4] = pw;
        }

        // O^T += V^T·P^T (Ps wave-private: lgkm ordering suffices)
#pragma unroll
        for (int ks = 0; ks < 2; ++ks) {
            bf16x8 bp = *(const bf16x8*)&Ps[(wave * 16 + l16) * 72 + ks * 32 + quad * 8];
#pragma unroll
            for (int j = 0; j < 4; ++j) {
                bf16x8 av = *(const bf16x8*)&Vts[(j * 16 + l16) * 64 +
                                                 ((ks * 4 + quad) ^ (l16 & 7)) * 8];
                o_acc[j] = MFMA16(av, bp, o_acc[j]);
            }
        }
    }

    // epilogue: quad-reduce l once, normalize, store (lane owns query qrow)
    const int b = bh >> 4, h = bh & 15;
    float l = lp;
    l += __shfl_xor(l, 16);
    l += __shfl_xor(l, 32);
    const float inv = 1.0f / l;
#pragma unroll
    for (int j = 0; j < 4; ++j) {
        uint2 o4;
        o4.x = pkbf(o_acc[j][0] * inv, o_acc[j][1] * inv);
        o4.y = pkbf(o_acc[j][2] * inv, o_acc[j][3] * inv);
        *(uint2*)&O[((size_t)(b * SS + qrow)) * EE + h * DD + j * 16 + quad * 4] = o4;
    }
}

extern "C" void kernel_launch(void* const* d_in, const int* in_sizes, int n_in,
                              void* d_out, int out_size, void* d_ws, size_t ws_size,
                              hipStream_t stream) {
    const float* x      = (const float*)d_in[0];  // [B,S,E] fp32
    const float* W_attn = (const float*)d_in[1];  // [3E,E] fp32
    const float* b_attn = (const float*)d_in[2];  // [3E] fp32
    const float* W_proj = (const float*)d_in[3];  // [E,E] fp32
    const float* b_proj = (const float*)d_in[4];  // [E] fp32
    float* out = (float*)d_out;                   // fp32 [B,S,E]

    // ws layout (u16 elems): xb 4.19M | wab 3.15M | wpb 1.05M | q 4.19M | k 4.19M | vt 4.19M
    u16* xb  = (u16*)d_ws;
    u16* wab = xb + (size_t)4096 * 1024;
    u16* wpb = wab + (size_t)3072 * 1024;
    u16* qw  = wpb + (size_t)1024 * 1024;
    u16* kw  = qw + (size_t)BB * HH * SS * DD;
    u16* vtw = kw + (size_t)BB * HH * SS * DD;
    u16* ow  = xb;                                 // xb dead after gemm_qkv

    convert_all<<<8192, 256, 0, stream>>>(x, W_attn, W_proj, xb);
    gemm_qkv<<<dim3(24, 32), 256, 0, stream>>>(xb, wab, b_attn, qw, kw, vtw);
    attn<<<dim3(32, 32), 256, 0, stream>>>(qw, kw, vtw, ow);
    gemm_proj<<<dim3(8, 32), 256, 0, stream>>>(ow, wpb, b_proj, out);
}

// Round 12
// 200.658 us; speedup vs baseline: 1.7567x; 1.0654x over previous
//
#include <hip/hip_runtime.h>
#include <hip/hip_bf16.h>

typedef unsigned short u16;
typedef unsigned int u32;
typedef float f32x4 __attribute__((ext_vector_type(4)));
typedef short bf16x8 __attribute__((ext_vector_type(8)));

// ---- constants (B=2, S=2048, E=1024, H=16, D=64) ----
#define BB 2
#define SS 2048
#define EE 1024
#define HH 16
#define DD 64
// q pre-scale: 1/sqrt(D) * log2(e) — scores land directly in exp2 domain.
#define QSCALE 0.18033688011f

__device__ __forceinline__ u16 f2bf(float f) {
    union { u32 i; float f; } x; x.f = f;
    return (u16)((x.i + 0x7FFFu + ((x.i >> 16) & 1u)) >> 16);
}
__device__ __forceinline__ u32 pkbf(float a, float b) {
    __hip_bfloat162 h = __float22bfloat162_rn(make_float2(a, b));
    union { __hip_bfloat162 h; u32 u; } c; c.h = h; return c.u;
}

#define MFMA16(a, b, c) __builtin_amdgcn_mfma_f32_16x16x32_bf16((a), (b), (c), 0, 0, 0)

// async global->LDS DMA, 16B per lane; LDS dest = wave-uniform base + lane*16
__device__ __forceinline__ void gld16(const u16* g, u16* l) {
    __builtin_amdgcn_global_load_lds(
        (const __attribute__((address_space(1))) void*)g,
        (__attribute__((address_space(3))) void*)l,
        16, 0, 0);
}

// ============================================================
// fused fp32 -> bf16 convert of x | W_attn | W_proj into contiguous ws
// ============================================================
__global__ __launch_bounds__(256) void convert_all(
    const float* __restrict__ x, const float* __restrict__ wa,
    const float* __restrict__ wp, u16* __restrict__ dst)
{
    const size_t n0 = (size_t)4096 * 1024;
    const size_t n1 = n0 + (size_t)3072 * 1024;
    size_t i = ((size_t)blockIdx.x * 256 + threadIdx.x) * 4;
    const float* s;
    size_t off;
    if (i < n0)      { s = x;  off = 0;  }
    else if (i < n1) { s = wa; off = n0; }
    else             { s = wp; off = n1; }
    float4 v = *(const float4*)(s + (i - off));
    uint2 o;
    o.x = pkbf(v.x, v.y);
    o.y = pkbf(v.z, v.w);
    *(uint2*)(dst + i) = o;
}

// ============================================================
// GEMM1 v3: qkv = x*W_attn^T + b_attn — 8-wave (512-thr) 128x128 tile.
// Wave-grid 2x4 (per-wave 64m x 32n, acc 4x2): same 768 blocks = 3/CU but
// 24 waves/CU (2x r11) to fill the DMA-drain stalls. Traffic unchanged.
// Staging: waves 0-3 DMA the A tile, waves 4-7 the B tile (16 chunks each).
// q (pre-scaled QSCALE) / k -> [B,H,S,D]; v -> V^T [B,H,D,S] via LDS
// transpose (T aliases As/Bs, two m-half passes). grid (24, 32).
// ============================================================
__global__ __launch_bounds__(512, 4) void gemm_qkv(
    const u16* __restrict__ A, const u16* __restrict__ B, const float* __restrict__ bias,
    u16* __restrict__ Qo, u16* __restrict__ Ko, u16* __restrict__ Vto)
{
    __shared__ __align__(16) u16 SMEM[16384];      // As[128*64] | Bs[128*64]; T aliases
    u16* As = SMEM;
    u16* Bs = SMEM + 8192;
    const int n0 = blockIdx.x * 128, m0 = blockIdx.y * 128;
    const int tid = threadIdx.x;
    const int wave = tid >> 6, lane = tid & 63;
    const int l16 = lane & 15, quad = lane >> 4;
    const int wm = wave >> 2, wn = wave & 3;       // 2x4 wave grid
    const int ldr = lane >> 3;
    const int csw = ((lane & 7) ^ ldr) * 8;        // swizzled k-chunk (elems)

    f32x4 acc[4][2];
#pragma unroll
    for (int i = 0; i < 4; ++i)
#pragma unroll
        for (int j = 0; j < 2; ++j) acc[i][j] = f32x4{0.f, 0.f, 0.f, 0.f};

    const int aorb = wave >> 2;                    // 0: stage A, 1: stage B
    u16* stgbuf = aorb ? Bs : As;
    const u16* stgsrc = aorb ? B : A;
    const int stgbase = aorb ? n0 : m0;

    for (int k0 = 0; k0 < 1024; k0 += 64) {
        __syncthreads();
#pragma unroll
        for (int t = 0; t < 4; ++t) {
            const int c = (wave & 3) * 4 + t;      // 0..15
            const int row = c * 8 + ldr;
            gld16(stgsrc + (size_t)(stgbase + row) * 1024 + k0 + csw,
                  &stgbuf[c * 512 + lane * 8]);
        }
        __syncthreads();
#pragma unroll
        for (int ks = 0; ks < 2; ++ks) {
            bf16x8 af[4], bf[2];
#pragma unroll
            for (int i = 0; i < 4; ++i)
                af[i] = *(const bf16x8*)&As[(wm * 64 + i * 16 + l16) * 64 +
                                            ((ks * 4 + quad) ^ (l16 & 7)) * 8];
#pragma unroll
            for (int j = 0; j < 2; ++j)
                bf[j] = *(const bf16x8*)&Bs[(wn * 32 + j * 16 + l16) * 64 +
                                            ((ks * 4 + quad) ^ (l16 & 7)) * 8];
#pragma unroll
            for (int i = 0; i < 4; ++i)
#pragma unroll
                for (int j = 0; j < 2; ++j)
                    acc[i][j] = MFMA16(af[i], bf[j], acc[i][j]);
        }
    }

    const int part = blockIdx.x >> 3;              // 0=q,1=k,2=v
    const int hbase = (blockIdx.x & 7) << 1;
    if (part != 2) {
        const int h = hbase + (wn >> 1);           // uniform per wave
#pragma unroll
        for (int j = 0; j < 2; ++j) {
            const int f = n0 + wn * 32 + j * 16 + l16;
            const int d = f & 63;
            const float bj = bias[f];
#pragma unroll
            for (int i = 0; i < 4; ++i) {
#pragma unroll
                for (int r = 0; r < 4; ++r) {
                    const int m = m0 + wm * 64 + i * 16 + quad * 4 + r;
                    const int b = m >> 11, s = m & 2047;
                    const float val = acc[i][j][r] + bj;
                    if (part == 0)
                        Qo[(((size_t)(b * HH + h)) * SS + s) * DD + d] = f2bf(val * QSCALE);
                    else
                        Ko[(((size_t)(b * HH + h)) * SS + s) * DD + d] = f2bf(val);
                }
            }
        }
    } else {
        // V: transpose C-tile (128 m x 128 f) through T (aliases SMEM),
        // two m-half passes, coalesced 8B stores to [B,H,D,S].
        u16* T = SMEM;                             // 128 x 72 = 18432 B
#pragma unroll
        for (int wmr = 0; wmr < 2; ++wmr) {
            __syncthreads();
            if (wm == wmr) {
#pragma unroll
                for (int j = 0; j < 2; ++j) {
                    const float bj = bias[n0 + wn * 32 + j * 16 + l16];
#pragma unroll
                    for (int i = 0; i < 4; ++i) {
                        uint2 pw;
                        pw.x = pkbf(acc[i][j][0] + bj, acc[i][j][1] + bj);
                        pw.y = pkbf(acc[i][j][2] + bj, acc[i][j][3] + bj);
                        *(uint2*)&T[(wn * 32 + j * 16 + l16) * 72 + i * 16 + quad * 4] = pw;
                    }
                }
            }
            __syncthreads();
            const int frow = tid >> 2;             // 0..127 (f_local)
            const int qtr = tid & 3;
            const int h = hbase + (frow >> 6);
            const int d = frow & 63;
            const int mg = m0 + wmr * 64;
            const int b = mg >> 11, sbase = mg & 2047;
            u16* dstrow = Vto + (((size_t)(b * HH + h)) * DD + d) * SS + sbase;
#pragma unroll
            for (int l = 0; l < 4; ++l) {
                const int mo = qtr * 16 + l * 4;
                *(uint2*)(dstrow + mo) = *(const uint2*)&T[frow * 72 + mo];
            }
        }
    }
}

// ============================================================
// GEMM2 v3: out = o*W_proj^T + b_proj (fp32) — 64x128 tile, 8 waves.
// grid (8, 64) = 512 blocks = 2/CU x 8 waves = 16 waves/CU (4x r11).
// Wave-grid 2x4 (per-wave 32m x 32n, acc 2x2). LDS 24.6 KB.
// ============================================================
__global__ __launch_bounds__(512, 4) void gemm_proj(
    const u16* __restrict__ A, const u16* __restrict__ B, const float* __restrict__ bias,
    float* __restrict__ out)
{
    __shared__ __align__(16) u16 SMEM[12288];      // As[64*64] | Bs[128*64]
    u16* As = SMEM;
    u16* Bs = SMEM + 4096;
    const int n0 = blockIdx.x * 128, m0 = blockIdx.y * 64;
    const int tid = threadIdx.x;
    const int wave = tid >> 6, lane = tid & 63;
    const int l16 = lane & 15, quad = lane >> 4;
    const int wm = wave >> 2, wn = wave & 3;       // 2x4 wave grid
    const int ldr = lane >> 3;
    const int csw = ((lane & 7) ^ ldr) * 8;

    f32x4 acc[2][2];
#pragma unroll
    for (int i = 0; i < 2; ++i)
#pragma unroll
        for (int j = 0; j < 2; ++j) acc[i][j] = f32x4{0.f, 0.f, 0.f, 0.f};

    for (int k0 = 0; k0 < 1024; k0 += 64) {
        __syncthreads();
#pragma unroll
        for (int t = 0; t < 3; ++t) {
            const int c = wave * 3 + t;            // 0..23: A chunks 0-7, B 8-23
            if (c < 8) {
                const int row = c * 8 + ldr;
                gld16(A + (size_t)(m0 + row) * 1024 + k0 + csw, &As[c * 512 + lane * 8]);
            } else {
                const int c2 = c - 8;
                const int row = c2 * 8 + ldr;
                gld16(B + (size_t)(n0 + row) * 1024 + k0 + csw, &Bs[c2 * 512 + lane * 8]);
            }
        }
        __syncthreads();
#pragma unroll
        for (int ks = 0; ks < 2; ++ks) {
            bf16x8 af[2], bf[2];
#pragma unroll
            for (int i = 0; i < 2; ++i)
                af[i] = *(const bf16x8*)&As[(wm * 32 + i * 16 + l16) * 64 +
                                            ((ks * 4 + quad) ^ (l16 & 7)) * 8];
#pragma unroll
            for (int j = 0; j < 2; ++j)
                bf[j] = *(const bf16x8*)&Bs[(wn * 32 + j * 16 + l16) * 64 +
                                            ((ks * 4 + quad) ^ (l16 & 7)) * 8];
#pragma unroll
            for (int i = 0; i < 2; ++i)
#pragma unroll
                for (int j = 0; j < 2; ++j)
                    acc[i][j] = MFMA16(af[i], bf[j], acc[i][j]);
        }
    }
#pragma unroll
    for (int j = 0; j < 2; ++j) {
        const int f = n0 + wn * 32 + j * 16 + l16;
        const float bj = bias[f];
#pragma unroll
        for (int i = 0; i < 2; ++i) {
#pragma unroll
            for (int r = 0; r < 4; ++r) {
                const int m = m0 + wm * 32 + i * 16 + quad * 4 + r;
                out[(size_t)m * EE + f] = acc[i][j][r] + bj;
            }
        }
    }
}

// ============================================================
// MFMA flash attention v5 (r11, unchanged): one q-tile per block,
// no-max softmax, gld16-staged K/V, XOR-swizzled LDS.
// grid (32,32) = 1024 blocks, 4 blocks/CU. qb = 31-bx (longest first).
// ============================================================
__global__ __launch_bounds__(256, 4) void attn(
    const u16* __restrict__ Q, const u16* __restrict__ K, const u16* __restrict__ VT,
    u16* __restrict__ O)
{
    const int qb = 31 - (int)blockIdx.x;   // longest first
    const int bh = blockIdx.y;
    const int tid = threadIdx.x;
    const int wave = tid >> 6, lane = tid & 63;
    const int l16 = lane & 15, quad = lane >> 4;
    const int ldr = lane >> 3;
    const int csw = ((lane & 7) ^ ldr) * 8;
    __shared__ __align__(16) u16 Ks[64 * 64];
    __shared__ __align__(16) u16 Vts[64 * 64];
    __shared__ __align__(16) u16 Ps[64 * 72];

    const u16* qptr = Q + (size_t)bh * SS * DD;
    const u16* kptr = K + (size_t)bh * SS * DD;
    const u16* vtptr = VT + (size_t)bh * DD * SS;

    const int qrow = qb * 64 + wave * 16 + l16;   // this lane's query
    bf16x8 bq[2];
#pragma unroll
    for (int ks = 0; ks < 2; ++ks)
        bq[ks] = *(const bf16x8*)(qptr + (size_t)qrow * DD + ks * 32 + quad * 8);

    float lp = 0.f;                        // per-lane partial l
    f32x4 o_acc[4];
#pragma unroll
    for (int j = 0; j < 4; ++j) o_acc[j] = f32x4{0.f, 0.f, 0.f, 0.f};

    for (int kb = 0; kb <= qb; ++kb) {
        const int k0 = kb * 64;
        __syncthreads();
#pragma unroll
        for (int t = 0; t < 2; ++t) {
            const int a0 = wave * 2 + t;
            const int row = a0 * 8 + ldr;
            gld16(kptr + (size_t)(k0 + row) * DD + csw, &Ks[a0 * 512 + lane * 8]);
            gld16(vtptr + (size_t)row * SS + k0 + csw, &Vts[a0 * 512 + lane * 8]);
        }
        __syncthreads();

        // S^T = K·Q^T
        f32x4 s[4];
#pragma unroll
        for (int j = 0; j < 4; ++j) s[j] = f32x4{0.f, 0.f, 0.f, 0.f};
#pragma unroll
        for (int ks = 0; ks < 2; ++ks) {
#pragma unroll
            for (int j = 0; j < 4; ++j) {
                bf16x8 ak = *(const bf16x8*)&Ks[(j * 16 + l16) * 64 +
                                                ((ks * 4 + quad) ^ (l16 & 7)) * 8];
                s[j] = MFMA16(ak, bq[ks], s[j]);
            }
        }

        // ---- no-max softmax: p = exp2(s'), mask only on the diagonal tile ----
        if (kb == qb) {
#pragma unroll
            for (int j = 0; j < 4; ++j)
#pragma unroll
                for (int r = 0; r < 4; ++r) {
                    const int key = k0 + j * 16 + quad * 4 + r;
                    if (key > qrow) s[j][r] = -INFINITY;   // exp2 -> 0
                }
        }
#pragma unroll
        for (int j = 0; j < 4; ++j) {
            const float p0 = __builtin_amdgcn_exp2f(s[j][0]);
            const float p1 = __builtin_amdgcn_exp2f(s[j][1]);
            const float p2 = __builtin_amdgcn_exp2f(s[j][2]);
            const float p3 = __builtin_amdgcn_exp2f(s[j][3]);
            lp += (p0 + p1) + (p2 + p3);
            uint2 pw; pw.x = pkbf(p0, p1); pw.y = pkbf(p2, p3);
            *(uint2*)&Ps[(wave * 16 + l16) * 72 + j * 16 + quad * 4] = pw;
        }

        // O^T += V^T·P^T (Ps wave-private: lgkm ordering suffices)
#pragma unroll
        for (int ks = 0; ks < 2; ++ks) {
            bf16x8 bp = *(const bf16x8*)&Ps[(wave * 16 + l16) * 72 + ks * 32 + quad * 8];
#pragma unroll
            for (int j = 0; j < 4; ++j) {
                bf16x8 av = *(const bf16x8*)&Vts[(j * 16 + l16) * 64 +
                                                 ((ks * 4 + quad) ^ (l16 & 7)) * 8];
                o_acc[j] = MFMA16(av, bp, o_acc[j]);
            }
        }
    }

    // epilogue: quad-reduce l once, normalize, store (lane owns query qrow)
    const int b = bh >> 4, h = bh & 15;
    float l = lp;
    l += __shfl_xor(l, 16);
    l += __shfl_xor(l, 32);
    const float inv = 1.0f / l;
#pragma unroll
    for (int j = 0; j < 4; ++j) {
        uint2 o4;
        o4.x = pkbf(o_acc[j][0] * inv, o_acc[j][1] * inv);
        o4.y = pkbf(o_acc[j][2] * inv, o_acc[j][3] * inv);
        *(uint2*)&O[((size_t)(b * SS + qrow)) * EE + h * DD + j * 16 + quad * 4] = o4;
    }
}

extern "C" void kernel_launch(void* const* d_in, const int* in_sizes, int n_in,
                              void* d_out, int out_size, void* d_ws, size_t ws_size,
                              hipStream_t stream) {
    const float* x      = (const float*)d_in[0];  // [B,S,E] fp32
    const float* W_attn = (const float*)d_in[1];  // [3E,E] fp32
    const float* b_attn = (const float*)d_in[2];  // [3E] fp32
    const float* W_proj = (const float*)d_in[3];  // [E,E] fp32
    const float* b_proj = (const float*)d_in[4];  // [E] fp32
    float* out = (float*)d_out;                   // fp32 [B,S,E]

    // ws layout (u16 elems): xb 4.19M | wab 3.15M | wpb 1.05M | q 4.19M | k 4.19M | vt 4.19M
    u16* xb  = (u16*)d_ws;
    u16* wab = xb + (size_t)4096 * 1024;
    u16* wpb = wab + (size_t)3072 * 1024;
    u16* qw  = wpb + (size_t)1024 * 1024;
    u16* kw  = qw + (size_t)BB * HH * SS * DD;
    u16* vtw = kw + (size_t)BB * HH * SS * DD;
    u16* ow  = xb;                                 // xb dead after gemm_qkv

    convert_all<<<8192, 256, 0, stream>>>(x, W_attn, W_proj, xb);
    gemm_qkv<<<dim3(24, 32), 512, 0, stream>>>(xb, wab, b_attn, qw, kw, vtw);
    attn<<<dim3(32, 32), 256, 0, stream>>>(qw, kw, vtw, ow);
    gemm_proj<<<dim3(8, 64), 512, 0, stream>>>(ow, wpb, b_proj, out);
}